// Round 3
// baseline (310.261 us; speedup 1.0000x reference)
//
#include <hip/hip_runtime.h>
#include <cstdint>

// CausalSelfAttention fused pipeline, all-bf16 MFMA path.
// Phases: [x->bf16 swz] [W^T->bf16 swz] -> QKV GEMM -> flash attn -> out GEMM.
// V is stored TRANSPOSED (Vt[b,h][d][s]) so attn PV reads V^T fragments
// straight from global (L2-resident; m169: no V staging when cache-fit).
// ws layout (ushort elems): Q[8.39M] K[8.39M] Vt[8.39M] AO[8.39M] Xb[8.39M] WtQ[786K] WtO[262K]

#define DEVI __device__ __forceinline__

typedef __bf16 bf8 __attribute__((ext_vector_type(8)));
typedef float f4 __attribute__((ext_vector_type(4)));
typedef unsigned short us8 __attribute__((ext_vector_type(8)));
typedef unsigned short us4 __attribute__((ext_vector_type(4)));

typedef const unsigned int __attribute__((address_space(1))) gu32;
typedef unsigned int __attribute__((address_space(3))) lu32;

DEVI unsigned short f2bf(float f) {  // RNE f32->bf16 (no NaN inputs here)
  unsigned u = __builtin_bit_cast(unsigned, f);
  u += 0x7fffu + ((u >> 16) & 1u);
  return (unsigned short)(u >> 16);
}

DEVI void gl_lds16(const void* g, void* l) {
  // async global->LDS, 16B/lane, dest = wave-uniform base + lane*16
  __builtin_amdgcn_global_load_lds((gu32*)g, (lu32*)l, 16, 0, 0);
}

DEVI bf8 comb(us4 a, us4 b) {
  us8 r;
  r[0]=a[0]; r[1]=a[1]; r[2]=a[2]; r[3]=a[3];
  r[4]=b[0]; r[5]=b[1]; r[6]=b[2]; r[7]=b[3];
  return __builtin_bit_cast(bf8, r);
}

// ---------------- prep: x (f32 [16384][512]) -> bf16, chunk-swizzled ----------------
// storage: within each row, 16B chunk c stored at (c&~7)|((c&7)^(row&7))
__global__ __launch_bounds__(256) void k_convert_x(const float* __restrict__ x,
                                                   unsigned short* __restrict__ xb) {
  int c = blockIdx.x * 256 + threadIdx.x;   // 1,048,576 chunks
  int row = c >> 6, cl = c & 63;
  const float* s = x + ((size_t)row << 9) + (cl << 3);
  float4 a = *(const float4*)s;
  float4 b = *(const float4*)(s + 4);
  us8 o;
  o[0]=f2bf(a.x); o[1]=f2bf(a.y); o[2]=f2bf(a.z); o[3]=f2bf(a.w);
  o[4]=f2bf(b.x); o[5]=f2bf(b.y); o[6]=f2bf(b.z); o[7]=f2bf(b.w);
  int p = (cl & ~7) | ((cl & 7) ^ (row & 7));
  *(us8*)(xb + ((size_t)row << 9) + (p << 3)) = o;
}

// ------------- prep: W [512][N] f32 -> Wt [N][512] bf16, chunk-swizzled -------------
__global__ __launch_bounds__(256) void k_transpose_w(const float* __restrict__ W,
                                                     unsigned short* __restrict__ Wt, int N) {
  __shared__ float t[32][33];
  int k0 = blockIdx.x * 32, n0 = blockIdx.y * 32;
  int tx = threadIdx.x & 31, ty = threadIdx.x >> 5;
#pragma unroll
  for (int r = 0; r < 4; ++r)
    t[ty + r * 8][tx] = W[(size_t)(k0 + ty + r * 8) * N + n0 + tx];
  __syncthreads();
#pragma unroll
  for (int r = 0; r < 4; ++r) {
    int n = n0 + ty + r * 8, k = k0 + tx;
    int k2 = (k & ~63) | ((((k >> 3) & 7) ^ (n & 7)) << 3) | (k & 7);
    Wt[((size_t)n << 9) + k2] = f2bf(t[tx][ty + r * 8]);
  }
}

// ---------------- GEMM: C[M][col] = A[M][512] * Bt[col][512]^T + bias ----------------
// 128x128 tile, BK=64, 4 waves (2x2), each wave 64x64 via 4x4 16x16x32 mfma frags.
// EPI=0: QKV epilogue (scale Q by 0.125; K chunk-swz [b,h,s,d]; V transposed [b,h,d,s])
// EPI=1: f32 out + bias
template <int EPI>
__global__ __launch_bounds__(256, 2)
void k_gemm(const unsigned short* __restrict__ Ag, const unsigned short* __restrict__ Bg,
            const float* __restrict__ bias, float* __restrict__ Of,
            unsigned short* __restrict__ Oq, unsigned short* __restrict__ Ok,
            unsigned short* __restrict__ Ov) {
  __shared__ __align__(16) unsigned short lds[128 * 64 * 2];
  unsigned short* Al = lds;
  unsigned short* Bl = lds + 128 * 64;
  const int tid = threadIdx.x, wv = tid >> 6, lane = tid & 63, g = lane >> 4, cl = lane & 15;
  const int wm = wv >> 1, wn = wv & 1;
  const int row0 = blockIdx.x * 128, col0 = blockIdx.y * 128;
  f4 acc[4][4];
#pragma unroll
  for (int i = 0; i < 4; ++i)
#pragma unroll
    for (int j = 0; j < 4; ++j) acc[i][j] = (f4){0.f, 0.f, 0.f, 0.f};

  for (int kt = 0; kt < 8; ++kt) {
#pragma unroll
    for (int j = 0; j < 4; ++j) {
      int ci = wv * 4 + j;
      int gci = ci * 64 + lane;
      int r = gci >> 3, cc = gci & 7;
      gl_lds16(Ag + ((size_t)(row0 + r) << 9) + kt * 64 + cc * 8, Al + ci * 512);
      gl_lds16(Bg + ((size_t)(col0 + r) << 9) + kt * 64 + cc * 8, Bl + ci * 512);
    }
    __syncthreads();
#pragma unroll
    for (int kk = 0; kk < 2; ++kk) {
      bf8 af[4], bb[4];
#pragma unroll
      for (int mf = 0; mf < 4; ++mf) {
        int r = wm * 64 + mf * 16 + cl;
        int cc = (kk * 4 + g) ^ (r & 7);
        af[mf] = *(const bf8*)(Al + r * 64 + cc * 8);
      }
#pragma unroll
      for (int nf = 0; nf < 4; ++nf) {
        int r = wn * 64 + nf * 16 + cl;
        int cc = (kk * 4 + g) ^ (r & 7);
        bb[nf] = *(const bf8*)(Bl + r * 64 + cc * 8);
      }
#pragma unroll
      for (int mf = 0; mf < 4; ++mf)
#pragma unroll
        for (int nf = 0; nf < 4; ++nf)
          acc[mf][nf] = __builtin_amdgcn_mfma_f32_16x16x32_bf16(af[mf], bb[nf], acc[mf][nf], 0, 0, 0);
    }
    __syncthreads();
  }

#pragma unroll
  for (int nf = 0; nf < 4; ++nf) {
    int col = col0 + wn * 64 + nf * 16 + cl;
    float bv = bias[col];
#pragma unroll
    for (int mf = 0; mf < 4; ++mf) {
#pragma unroll
      for (int j = 0; j < 4; ++j) {
        int row = row0 + wm * 64 + mf * 16 + 4 * g + j;   // C/D: col=lane&15, row=4*(lane>>4)+reg
        float v = acc[mf][nf][j] + bv;
        if (EPI == 1) {
          Of[((size_t)row << 9) + col] = v;
        } else {
          int which = col >> 9, h = (col >> 6) & 7, d = col & 63;
          int b = row >> 11, s = row & 2047;
          if (which == 0) {
            Oq[(((size_t)b * 8 + h) * 2048 + s) * 64 + d] = f2bf(v * 0.125f);  // fold scale
          } else if (which == 1) {
            int d2 = (d & 7) | (((d >> 3) ^ (s & 7)) << 3);  // chunk swizzle for LDS path
            Ok[(((size_t)b * 8 + h) * 2048 + s) * 64 + d2] = f2bf(v);
          } else {
            Ov[(((size_t)b * 8 + h) * 64 + d) * 2048 + s] = f2bf(v);  // transposed V
          }
        }
      }
    }
  }
}

// ------------------------------- flash attention --------------------------------
// block = (b, h, 64-row q tile); 4 waves x 16 q rows. K via global_load_lds (swz rows).
// V^T fragments direct from global (L2-resident). P transposed via per-wave LDS,
// standard MFMA A mapping (lane: row=cl, k=g*8+j).
__global__ __launch_bounds__(256, 2)
void k_attn(const unsigned short* __restrict__ Q, const unsigned short* __restrict__ K,
            const unsigned short* __restrict__ Vt, const float* __restrict__ rel,
            unsigned short* __restrict__ AO) {
  __shared__ __align__(16) unsigned short Kl[64 * 64];
  __shared__ __align__(16) unsigned short Pl[4][16 * 68];
  const int tid = threadIdx.x, wv = tid >> 6, lane = tid & 63, g = lane >> 4, cl = lane & 15;
  // block-id swizzle: 8 batches sharing a rel_pos panel land on one XCD (bid%8 const)
  int bid = blockIdx.x;
  int glo = bid & 7, rest = bid >> 3;
  int b = rest & 7, ghi = rest >> 3;
  int grp = ghi * 8 + glo;
  int h = grp >> 5, qt = grp & 31;
  int qb = qt << 6;
  size_t bhoff = (((size_t)b << 3) + h) * (size_t)(2048 * 64);
  const unsigned short* Qp = Q + bhoff;
  const unsigned short* Kp = K + bhoff;
  const unsigned short* Vp = Vt + bhoff;   // [d][s] layout
  const float* relp = rel + ((size_t)h << 22);
  const int qrb = qb + wv * 16;

  bf8 qf[2];
#pragma unroll
  for (int kk = 0; kk < 2; ++kk)
    qf[kk] = *(const bf8*)(Qp + ((size_t)(qrb + cl) << 6) + kk * 32 + g * 8);

  f4 oa[4];
  float mrun[4], lrun[4];
#pragma unroll
  for (int j = 0; j < 4; ++j) { mrun[j] = -1e30f; lrun[j] = 0.f; }
#pragma unroll
  for (int ct = 0; ct < 4; ++ct) oa[ct] = (f4){0.f, 0.f, 0.f, 0.f};

  for (int kt = 0; kt <= qt; ++kt) {
    int kb = kt << 6;
#pragma unroll
    for (int j2 = 0; j2 < 2; ++j2) {               // K tile: 8KB via global_load_lds
      int ci = wv * 2 + j2;
      int gci = ci * 64 + lane;
      int r = gci >> 3, cc = gci & 7;
      gl_lds16(Kp + ((size_t)(kb + r) << 6) + cc * 8, Kl + ci * 512);
    }
    __syncthreads();

    f4 sa[4];
#pragma unroll
    for (int ct = 0; ct < 4; ++ct) sa[ct] = (f4){0.f, 0.f, 0.f, 0.f};
#pragma unroll
    for (int kk = 0; kk < 2; ++kk) {
#pragma unroll
      for (int ct = 0; ct < 4; ++ct) {
        int r = ct * 16 + cl;
        int cc = (kk * 4 + g) ^ (r & 7);
        bf8 kf = *(const bf8*)(Kl + r * 64 + cc * 8);
        sa[ct] = __builtin_amdgcn_mfma_f32_16x16x32_bf16(qf[kk], kf, sa[ct], 0, 0, 0);
      }
    }
    // rel_pos + causal mask (scale already folded into Q)
#pragma unroll
    for (int ct = 0; ct < 4; ++ct) {
      int kcol = kb + ct * 16 + cl;
#pragma unroll
      for (int j = 0; j < 4; ++j) {
        int qrow = qrb + 4 * g + j;
        float sv = sa[ct][j] + relp[((size_t)qrow << 11) + kcol];
        sa[ct][j] = (kcol > qrow) ? -1e30f : sv;
      }
    }
    // wave-parallel online softmax (rows live in 16-lane groups)
    float al[4], mx[4];
#pragma unroll
    for (int j = 0; j < 4; ++j) {
      float m0 = fmaxf(fmaxf(sa[0][j], sa[1][j]), fmaxf(sa[2][j], sa[3][j]));
      m0 = fmaxf(m0, __shfl_xor(m0, 1, 16));
      m0 = fmaxf(m0, __shfl_xor(m0, 2, 16));
      m0 = fmaxf(m0, __shfl_xor(m0, 4, 16));
      m0 = fmaxf(m0, __shfl_xor(m0, 8, 16));
      float mn = fmaxf(mrun[j], m0);
      al[j] = __expf(mrun[j] - mn);
      mrun[j] = mn;
      mx[j] = mn;
    }
#pragma unroll
    for (int ct = 0; ct < 4; ++ct)
#pragma unroll
      for (int j = 0; j < 4; ++j) sa[ct][j] = __expf(sa[ct][j] - mx[j]);
#pragma unroll
    for (int j = 0; j < 4; ++j) {
      float rs = sa[0][j] + sa[1][j] + sa[2][j] + sa[3][j];
      rs += __shfl_xor(rs, 1, 16);
      rs += __shfl_xor(rs, 2, 16);
      rs += __shfl_xor(rs, 4, 16);
      rs += __shfl_xor(rs, 8, 16);
      lrun[j] = lrun[j] * al[j] + rs;
    }
#pragma unroll
    for (int ct = 0; ct < 4; ++ct) {
      oa[ct][0] *= al[0]; oa[ct][1] *= al[1]; oa[ct][2] *= al[2]; oa[ct][3] *= al[3];
    }
    // P -> bf16 -> per-wave LDS transpose (write C-layout, read A-layout).
    // Same-wave DS ops are in-order; no barrier needed.
    unsigned short* pw = Pl[wv];
#pragma unroll
    for (int ct = 0; ct < 4; ++ct)
#pragma unroll
      for (int j = 0; j < 4; ++j)
        pw[(4 * g + j) * 68 + ct * 16 + cl] = f2bf(sa[ct][j]);
    // PV: A = P[q=cl][k=kk*32+g*8+j], B = Vt[d=ct*16+cl][k=kb+kk*32+g*8+j] (16B global)
#pragma unroll
    for (int kk = 0; kk < 2; ++kk) {
      us4 p0 = *(const us4*)(pw + cl * 68 + kk * 32 + g * 8);
      us4 p1 = *(const us4*)(pw + cl * 68 + kk * 32 + g * 8 + 4);
      bf8 pf = comb(p0, p1);
#pragma unroll
      for (int ct = 0; ct < 4; ++ct) {
        bf8 vf = *(const bf8*)(Vp + ((size_t)(ct * 16 + cl) << 11) + kb + kk * 32 + g * 8);
        oa[ct] = __builtin_amdgcn_mfma_f32_16x16x32_bf16(pf, vf, oa[ct], 0, 0, 0);
      }
    }
    __syncthreads();
  }
  // epilogue: O /= l, write bf16 [b][s][h*64+d] with chunk swizzle for out-GEMM staging
#pragma unroll
  for (int j = 0; j < 4; ++j) {
    float inv = 1.0f / lrun[j];
    int s = qrb + 4 * g + j;
#pragma unroll
    for (int ct = 0; ct < 4; ++ct) {
      int d = ct * 16 + cl;
      int d2 = (d & 7) | (((d >> 3) ^ (s & 7)) << 3);
      AO[(((size_t)b << 11) + s) * 512 + h * 64 + d2] = f2bf(oa[ct][j] * inv);
    }
  }
}

// ------------------------------------ launch ------------------------------------
extern "C" void kernel_launch(void* const* d_in, const int* in_sizes, int n_in,
                              void* d_out, int out_size, void* d_ws, size_t ws_size,
                              hipStream_t stream) {
  const float* x    = (const float*)d_in[0];
  const float* Wqkv = (const float*)d_in[1];
  const float* bqkv = (const float*)d_in[2];
  const float* Wout = (const float*)d_in[3];
  const float* bout = (const float*)d_in[4];
  const float* rel  = (const float*)d_in[5];
  float* out = (float*)d_out;

  unsigned short* Qw  = (unsigned short*)d_ws;
  unsigned short* Kw  = Qw  + 8388608;
  unsigned short* Vw  = Kw  + 8388608;
  unsigned short* AOw = Vw  + 8388608;
  unsigned short* Xb  = AOw + 8388608;
  unsigned short* WtQ = Xb  + 8388608;
  unsigned short* WtO = WtQ + 786432;

  k_convert_x<<<dim3(4096), dim3(256), 0, stream>>>(x, Xb);
  k_transpose_w<<<dim3(16, 48), dim3(256), 0, stream>>>(Wqkv, WtQ, 1536);
  k_transpose_w<<<dim3(16, 16), dim3(256), 0, stream>>>(Wout, WtO, 512);
  k_gemm<0><<<dim3(128, 12), dim3(256), 0, stream>>>(Xb, WtQ, bqkv, nullptr, Qw, Kw, Vw);
  k_attn<<<dim3(2048), dim3(256), 0, stream>>>(Qw, Kw, Vw, rel, AOw);
  k_gemm<1><<<dim3(128, 4), dim3(256), 0, stream>>>(AOw, WtO, bout, out, nullptr, nullptr, nullptr);
}